// Round 2
// baseline (241.119 us; speedup 1.0000x reference)
//
#include <hip/hip_runtime.h>
#include <hip/hip_bf16.h>

// Problem constants (DynamicGraphPruning: B=8, H=W=128, C=256, PROJ=128)
#define Bn   8
#define Ln   16384     // H*W
#define Cn   256
#define Pn   128       // PROJ
#define En   65024     // 4*127*128 grid edges
#define LN_EPSf 1e-5f
#define ROWS 16        // rows per block in proj kernel

typedef __attribute__((ext_vector_type(8))) short short8;

__device__ __forceinline__ float bf2f(unsigned short u) {
    union { unsigned int i; float f; } v;
    v.i = ((unsigned int)u) << 16;
    return v.f;
}

// Kernel 1: h = features @ W_proj + b_proj; LayerNorm; L2-normalize -> sem (bf16)
// grid = B*L/ROWS blocks, 128 threads (one thread per output column p, ROWS rows).
__global__ __launch_bounds__(128)
void proj_ln_kernel(const float* __restrict__ F, const float* __restrict__ Wp,
                    const float* __restrict__ bp, const float* __restrict__ gam,
                    const float* __restrict__ bet, __hip_bfloat16* __restrict__ sem)
{
    __shared__ float feat[ROWS * Cn];         // 16 KB
    __shared__ float red[2][ROWS][2];

    const int t    = threadIdx.x;             // 0..127
    const int wid  = t >> 6;
    const int lane = t & 63;
    const size_t row0 = (size_t)blockIdx.x * ROWS;   // global row = b*L + l

    // Stage ROWS*Cn = 4096 contiguous floats via float4 (coalesced)
    const float4* s4 = (const float4*)(F + row0 * Cn);
    float4* f4 = (float4*)feat;
#pragma unroll
    for (int i = 0; i < 8; i++) f4[t + i * 128] = s4[t + i * 128];
    __syncthreads();

    const int p = t;   // output column 0..127
    float acc[ROWS];
#pragma unroll
    for (int r = 0; r < ROWS; r++) acc[r] = 0.f;

    for (int c = 0; c < Cn; c += 4) {
        const float w0 = Wp[(c + 0) * Pn + p];
        const float w1 = Wp[(c + 1) * Pn + p];
        const float w2 = Wp[(c + 2) * Pn + p];
        const float w3 = Wp[(c + 3) * Pn + p];
#pragma unroll
        for (int r = 0; r < ROWS; r++) {
            const float4 f = *(const float4*)&feat[r * Cn + c];
            acc[r] = fmaf(f.x, w0, fmaf(f.y, w1, fmaf(f.z, w2, fmaf(f.w, w3, acc[r]))));
        }
    }

    const float bpv = bp[p], g = gam[p], bt = bet[p];

    // LayerNorm stats over p (128 threads = 2 waves)
#pragma unroll
    for (int r = 0; r < ROWS; r++) {
        float h = acc[r] + bpv;
        acc[r] = h;
        float s = h, q = h * h;
        for (int o = 32; o; o >>= 1) {
            s += __shfl_xor(s, o);
            q += __shfl_xor(q, o);
        }
        if (lane == 0) { red[wid][r][0] = s; red[wid][r][1] = q; }
    }
    __syncthreads();

    float hn[ROWS];
#pragma unroll
    for (int r = 0; r < ROWS; r++) {
        const float s  = red[0][r][0] + red[1][r][0];
        const float q  = red[0][r][1] + red[1][r][1];
        const float mu = s * (1.f / Pn);
        const float var = q * (1.f / Pn) - mu * mu;
        const float inv = rsqrtf(var + LN_EPSf);
        hn[r] = (acc[r] - mu) * inv * g + bt;
    }
    __syncthreads();   // before reusing red

    // L2 norm over p
#pragma unroll
    for (int r = 0; r < ROWS; r++) {
        float q = hn[r] * hn[r];
        for (int o = 32; o; o >>= 1) q += __shfl_xor(q, o);
        if (lane == 0) red[wid][r][0] = q;
    }
    __syncthreads();

#pragma unroll
    for (int r = 0; r < ROWS; r++) {
        const float nrm = sqrtf(red[0][r][0] + red[1][r][0]);
        const float rin = 1.f / fmaxf(nrm, 1e-12f);
        sem[(row0 + r) * Pn + p] = __float2bfloat16(hn[r] * rin);
    }
}

// Kernel 2: per-edge semantic dot + spatial sim; outputs are FLOAT32.
// 16 lanes per edge, 16 edges per 256-thread block.
__global__ __launch_bounds__(256)
void edge_kernel(const __hip_bfloat16* __restrict__ sem,
                 const float* __restrict__ coords,
                 const int* __restrict__ eidx,
                 const float* __restrict__ alpha,
                 float* __restrict__ out_idx,
                 float* __restrict__ out_w)
{
    const int t   = threadIdx.x;
    const int g   = blockIdx.x * 16 + (t >> 4);   // flat edge id = b*E + e
    const int sub = t & 15;
    const int b   = g / En;

    const int src = eidx[(size_t)g * 2 + 0];
    const int dst = eidx[(size_t)g * 2 + 1];

    const size_t srow = ((size_t)b * Ln + src) * Pn;
    const size_t drow = ((size_t)b * Ln + dst) * Pn;

    const short8 sv = *(const short8*)(sem + srow + sub * 8);
    const short8 dv = *(const short8*)(sem + drow + sub * 8);

    float dotv = 0.f;
#pragma unroll
    for (int j = 0; j < 8; j++)
        dotv = fmaf(bf2f((unsigned short)sv[j]), bf2f((unsigned short)dv[j]), dotv);

    // reduce across the 16 lanes of this edge
    for (int o = 1; o < 16; o <<= 1) dotv += __shfl_xor(dotv, o);

    if (sub == 0) {
        const float a = 1.f / (1.f + expf(-alpha[0]));
        const size_t sc = ((size_t)b * Ln + src) * 2;
        const size_t dc = ((size_t)b * Ln + dst) * 2;
        const float ddx = coords[sc + 0] - coords[dc + 0];
        const float ddy = coords[sc + 1] - coords[dc + 1];
        const float dist = sqrtf(ddx * ddx + ddy * ddy + 1e-8f);
        const float ssim = 1.f - dist / 1.414f;
        const float wgt  = a * dotv + (1.f - a) * ssim;
        out_w[g] = wgt;
        out_idx[(size_t)g * 2 + 0] = (float)src;
        out_idx[(size_t)g * 2 + 1] = (float)dst;
    }
}

extern "C" void kernel_launch(void* const* d_in, const int* in_sizes, int n_in,
                              void* d_out, int out_size, void* d_ws, size_t ws_size,
                              hipStream_t stream) {
    const float* F      = (const float*)d_in[0];   // (B,L,C)
    const float* coords = (const float*)d_in[1];   // (B,L,2)
    const int*   eidx   = (const int*)d_in[2];     // (B,E,2)
    const float* alpha  = (const float*)d_in[3];   // scalar
    const float* Wp     = (const float*)d_in[4];   // (C,P)
    const float* bp     = (const float*)d_in[5];   // (P,)
    const float* gam    = (const float*)d_in[6];   // (P,)
    const float* bet    = (const float*)d_in[7];   // (P,)

    float* out     = (float*)d_out;                 // f32 outputs, concat order:
    float* out_idx = out;                           // edge_index (B,E,2) as f32
    float* out_w   = out + (size_t)Bn * En * 2;     // edge_weights (B,E) as f32
    __hip_bfloat16* sem = (__hip_bfloat16*)d_ws;    // 32 MB scratch (bf16 sem)

    proj_ln_kernel<<<(Bn * Ln) / ROWS, 128, 0, stream>>>(F, Wp, bp, gam, bet, sem);
    edge_kernel<<<(Bn * En) / 16, 256, 0, stream>>>(sem, coords, eidx, alpha, out_idx, out_w);
}

// Round 3
// 98.027 us; speedup vs baseline: 2.4597x; 2.4597x over previous
//
#include <hip/hip_runtime.h>
#include <hip/hip_bf16.h>

// Problem constants (DynamicGraphPruning: B=8, H=W=128, C=256, PROJ=128)
#define Bn   8
#define Ln   16384     // H*W
#define Cn   256
#define Pn   128       // PROJ
#define En   65024     // 4*127*128 grid edges
#define LN_EPSf 1e-5f
#define TM   64        // rows per block in MFMA proj kernel

typedef __attribute__((ext_vector_type(8))) short short8;   // bf16x8 MFMA frag
typedef __attribute__((ext_vector_type(4))) float f32x4;    // MFMA accum frag

__device__ __forceinline__ float bf2f(unsigned short u) {
    union { unsigned int i; float f; } v;
    v.i = ((unsigned int)u) << 16;
    return v.f;
}
__device__ __forceinline__ unsigned short f2bf(float x) {
    __hip_bfloat16 h = __float2bfloat16(x);   // RNE
    return *reinterpret_cast<unsigned short*>(&h);
}

// ---------------------------------------------------------------------------
// Kernel 0: W (C x P, f32) -> Wt (P x C, bf16) via LDS transpose. grid=4.
__global__ __launch_bounds__(256)
void wt_prep(const float* __restrict__ W, __hip_bfloat16* __restrict__ Wt)
{
    __shared__ float tile[64 * 128];          // 32 KB: 64 c-rows x 128 p
    const int t  = threadIdx.x;
    const int c0 = blockIdx.x * 64;

    const float* src = W + (size_t)c0 * Pn;
#pragma unroll
    for (int i = 0; i < 32; i++) tile[t + i * 256] = src[t + i * 256];
    __syncthreads();

    const int p  = t >> 1;
    const int ch = (t & 1) * 32;
    __hip_bfloat16* dst = Wt + (size_t)p * Cn + c0 + ch;
#pragma unroll
    for (int c = 0; c < 32; c++) {
        unsigned short v = f2bf(tile[(ch + c) * Pn + p]);
        *reinterpret_cast<unsigned short*>(dst + c) = v;
    }
}

// ---------------------------------------------------------------------------
// Kernel 1: h = F @ W + b; LayerNorm; L2-normalize -> sem (bf16), via bf16 MFMA.
// Block: 256 threads = 4 waves. TM=64 rows/block; wave w owns cols [32w,32w+32).
__global__ __launch_bounds__(256)
void proj_mfma_kernel(const float* __restrict__ F,
                      const __hip_bfloat16* __restrict__ Wt,
                      const float* __restrict__ bp, const float* __restrict__ gam,
                      const float* __restrict__ bet, __hip_bfloat16* __restrict__ sem)
{
    __shared__ char Abuf[TM * Cn * 2];        // 32 KB bf16, XOR-swizzled rows
    __shared__ float red[4][TM][2];           // cross-wave LN reductions (2 KB)

    const int t    = threadIdx.x;
    const int w    = t >> 6;
    const int lane = t & 63;
    const int cl   = lane & 15;               // MFMA col / A-row sub-index
    const int lg   = lane >> 4;               // k-group / row-group
    const size_t row0 = (size_t)blockIdx.x * TM;

    // ---- B fragments: wave's 32-col slice x 8 K-steps, from global Wt (L2)
    short8 bfrag[2][8];
#pragma unroll
    for (int n = 0; n < 2; n++)
#pragma unroll
        for (int ks = 0; ks < 8; ks++) {
            const __hip_bfloat16* src =
                Wt + (size_t)(w * 32 + n * 16 + cl) * Cn + ks * 32 + lg * 8;
            bfrag[n][ks] = *(const short8*)src;
        }

    // ---- Stage A: 64x256 f32 -> bf16 LDS, swizzled byte = row*512 + (kc*16 ^ ((row&7)<<4))
    {
        const float* src = F + (row0 << 8);   // row0 * 256
#pragma unroll
        for (int j = 0; j < 8; j++) {
            const int ci  = t + j * 256;      // chunk id 0..2047 (8 f32 each)
            const int row = ci >> 5;
            const int kc  = ci & 31;
            const float4 g0 = *(const float4*)(src + (size_t)ci * 8);
            const float4 g1 = *(const float4*)(src + (size_t)ci * 8 + 4);
            short8 v;
            v[0] = (short)f2bf(g0.x); v[1] = (short)f2bf(g0.y);
            v[2] = (short)f2bf(g0.z); v[3] = (short)f2bf(g0.w);
            v[4] = (short)f2bf(g1.x); v[5] = (short)f2bf(g1.y);
            v[6] = (short)f2bf(g1.z); v[7] = (short)f2bf(g1.w);
            const int off = row * 512 + ((kc * 16) ^ ((row & 7) << 4));
            *(short8*)(Abuf + off) = v;
        }
    }
    __syncthreads();

    // ---- MFMA: acc[m][n] covers rows m*16.. and cols w*32+n*16..
    f32x4 acc[4][2] = {};
#pragma unroll
    for (int ks = 0; ks < 8; ks++) {
#pragma unroll
        for (int m = 0; m < 4; m++) {
            const int arow = m * 16 + cl;
            const int kb   = (ks * 64 + lg * 16) ^ ((arow & 7) << 4);
            const short8 af = *(const short8*)(Abuf + arow * 512 + kb);
#pragma unroll
            for (int n = 0; n < 2; n++)
                acc[m][n] = __builtin_amdgcn_mfma_f32_16x16x32_bf16(
                    af, bfrag[n][ks], acc[m][n], 0, 0, 0);
        }
    }

    // ---- Epilogue: bias, LayerNorm, L2-normalize, write bf16 sem.
    // C/D layout: col = cl, row(in 16) = lg*4 + r.
    const float b0 = bp[w * 32 + cl],      b1 = bp[w * 32 + 16 + cl];
    const float g0 = gam[w * 32 + cl],     g1 = gam[w * 32 + 16 + cl];
    const float be0 = bet[w * 32 + cl],    be1 = bet[w * 32 + 16 + cl];

    float hv[4][2][4];
#pragma unroll
    for (int m = 0; m < 4; m++)
#pragma unroll
        for (int r = 0; r < 4; r++) {
            const float h0 = acc[m][0][r] + b0;
            const float h1 = acc[m][1][r] + b1;
            hv[m][0][r] = h0; hv[m][1][r] = h1;
            float s = h0 + h1, q = h0 * h0 + h1 * h1;
#pragma unroll
            for (int o = 1; o < 16; o <<= 1) {
                s += __shfl_xor(s, o);
                q += __shfl_xor(q, o);
            }
            if (cl == 0) {
                red[w][m * 16 + lg * 4 + r][0] = s;
                red[w][m * 16 + lg * 4 + r][1] = q;
            }
        }
    __syncthreads();
    if (t < TM) {
        float s = 0.f, q = 0.f;
#pragma unroll
        for (int w2 = 0; w2 < 4; w2++) { s += red[w2][t][0]; q += red[w2][t][1]; }
        const float mu  = s * (1.f / Pn);
        const float var = q * (1.f / Pn) - mu * mu;
        red[0][t][0] = mu;
        red[0][t][1] = rsqrtf(var + LN_EPSf);
    }
    __syncthreads();

#pragma unroll
    for (int m = 0; m < 4; m++)
#pragma unroll
        for (int r = 0; r < 4; r++) {
            const int row = m * 16 + lg * 4 + r;
            const float mu  = red[0][row][0];
            const float inv = red[0][row][1];
            const float hn0 = (hv[m][0][r] - mu) * inv * g0 + be0;
            const float hn1 = (hv[m][1][r] - mu) * inv * g1 + be1;
            hv[m][0][r] = hn0; hv[m][1][r] = hn1;
        }
    __syncthreads();   // done reading mu/inv before red is reused

#pragma unroll
    for (int m = 0; m < 4; m++)
#pragma unroll
        for (int r = 0; r < 4; r++) {
            float q = hv[m][0][r] * hv[m][0][r] + hv[m][1][r] * hv[m][1][r];
#pragma unroll
            for (int o = 1; o < 16; o <<= 1) q += __shfl_xor(q, o);
            if (cl == 0) red[w][m * 16 + lg * 4 + r][0] = q;
        }
    __syncthreads();
    if (t < TM) {
        float q = 0.f;
#pragma unroll
        for (int w2 = 0; w2 < 4; w2++) q += red[w2][t][0];
        const float nrm = sqrtf(q);
        red[0][t][1] = 1.f / fmaxf(nrm, 1e-12f);
    }
    __syncthreads();

#pragma unroll
    for (int m = 0; m < 4; m++)
#pragma unroll
        for (int r = 0; r < 4; r++) {
            const int row = m * 16 + lg * 4 + r;
            const float rin = red[0][row][1];
#pragma unroll
            for (int n = 0; n < 2; n++) {
                const size_t col = w * 32 + n * 16 + cl;
                unsigned short v = f2bf(hv[m][n][r] * rin);
                *reinterpret_cast<unsigned short*>(
                    sem + (row0 + row) * Pn + col) = v;
            }
        }
}

// ---------------------------------------------------------------------------
// Kernel 2: per-edge semantic dot + spatial sim; outputs FLOAT32.
// 16 lanes per edge, 16 edges per 256-thread block.
__global__ __launch_bounds__(256)
void edge_kernel(const __hip_bfloat16* __restrict__ sem,
                 const float* __restrict__ coords,
                 const int* __restrict__ eidx,
                 const float* __restrict__ alpha,
                 float* __restrict__ out_idx,
                 float* __restrict__ out_w)
{
    const int t   = threadIdx.x;
    const int g   = blockIdx.x * 16 + (t >> 4);   // flat edge id = b*E + e
    const int sub = t & 15;
    const int b   = g / En;

    const int src = eidx[(size_t)g * 2 + 0];
    const int dst = eidx[(size_t)g * 2 + 1];

    const size_t srow = ((size_t)b * Ln + src) * Pn;
    const size_t drow = ((size_t)b * Ln + dst) * Pn;

    const short8 sv = *(const short8*)(sem + srow + sub * 8);
    const short8 dv = *(const short8*)(sem + drow + sub * 8);

    float dotv = 0.f;
#pragma unroll
    for (int j = 0; j < 8; j++)
        dotv = fmaf(bf2f((unsigned short)sv[j]), bf2f((unsigned short)dv[j]), dotv);

    for (int o = 1; o < 16; o <<= 1) dotv += __shfl_xor(dotv, o);

    if (sub == 0) {
        const float a = 1.f / (1.f + expf(-alpha[0]));
        const size_t sc = ((size_t)b * Ln + src) * 2;
        const size_t dc = ((size_t)b * Ln + dst) * 2;
        const float ddx = coords[sc + 0] - coords[dc + 0];
        const float ddy = coords[sc + 1] - coords[dc + 1];
        const float dist = sqrtf(ddx * ddx + ddy * ddy + 1e-8f);
        const float ssim = 1.f - dist / 1.414f;
        const float wgt  = a * dotv + (1.f - a) * ssim;
        out_w[g] = wgt;
        out_idx[(size_t)g * 2 + 0] = (float)src;
        out_idx[(size_t)g * 2 + 1] = (float)dst;
    }
}

extern "C" void kernel_launch(void* const* d_in, const int* in_sizes, int n_in,
                              void* d_out, int out_size, void* d_ws, size_t ws_size,
                              hipStream_t stream) {
    const float* F      = (const float*)d_in[0];   // (B,L,C)
    const float* coords = (const float*)d_in[1];   // (B,L,2)
    const int*   eidx   = (const int*)d_in[2];     // (B,E,2)
    const float* alpha  = (const float*)d_in[3];   // scalar
    const float* Wp     = (const float*)d_in[4];   // (C,P)
    const float* bp     = (const float*)d_in[5];   // (P,)
    const float* gam    = (const float*)d_in[6];   // (P,)
    const float* bet    = (const float*)d_in[7];   // (P,)

    float* out     = (float*)d_out;                 // f32 outputs, concat order:
    float* out_idx = out;                           // edge_index (B,E,2) as f32
    float* out_w   = out + (size_t)Bn * En * 2;     // edge_weights (B,E) as f32

    __hip_bfloat16* Wt  = (__hip_bfloat16*)d_ws;               // 64 KB
    __hip_bfloat16* sem = (__hip_bfloat16*)((char*)d_ws + Cn * Pn * 2); // 32 MB

    wt_prep<<<4, 256, 0, stream>>>(Wp, Wt);
    proj_mfma_kernel<<<(Bn * Ln) / TM, 256, 0, stream>>>(F, Wt, bp, gam, bet, sem);
    edge_kernel<<<(Bn * En) / 16, 256, 0, stream>>>(sem, coords, eidx, alpha, out_idx, out_w);
}

// Round 4
// 87.121 us; speedup vs baseline: 2.7676x; 1.1252x over previous
//
#include <hip/hip_runtime.h>
#include <hip/hip_bf16.h>

// Problem constants (DynamicGraphPruning: B=8, H=W=128, C=256, PROJ=128)
#define Bn   8
#define Ln   16384     // H*W
#define Cn   256
#define Pn   128       // PROJ
#define En   65024     // 4*127*128 grid edges
#define LN_EPSf 1e-5f
#define TM   64        // rows per block in MFMA proj kernel

typedef __attribute__((ext_vector_type(8))) short short8;   // bf16x8 MFMA frag
typedef __attribute__((ext_vector_type(4))) float f32x4;    // MFMA accum frag

__device__ __forceinline__ float bf2f(unsigned short u) {
    union { unsigned int i; float f; } v;
    v.i = ((unsigned int)u) << 16;
    return v.f;
}
__device__ __forceinline__ unsigned short f2bf(float x) {
    __hip_bfloat16 h = __float2bfloat16(x);   // RNE
    return *reinterpret_cast<unsigned short*>(&h);
}

// ---------------------------------------------------------------------------
// Kernel 0: W (C x P, f32) -> Wt (P x C, bf16) via LDS transpose. grid=4.
__global__ __launch_bounds__(256)
void wt_prep(const float* __restrict__ W, __hip_bfloat16* __restrict__ Wt)
{
    __shared__ float tile[64 * 128];          // 32 KB: 64 c-rows x 128 p
    const int t  = threadIdx.x;
    const int c0 = blockIdx.x * 64;

    const float* src = W + (size_t)c0 * Pn;
#pragma unroll
    for (int i = 0; i < 32; i++) tile[t + i * 256] = src[t + i * 256];
    __syncthreads();

    const int p  = t >> 1;
    const int ch = (t & 1) * 32;
    __hip_bfloat16* dst = Wt + (size_t)p * Cn + c0 + ch;
#pragma unroll
    for (int c = 0; c < 32; c++) {
        unsigned short v = f2bf(tile[(ch + c) * Pn + p]);
        *reinterpret_cast<unsigned short*>(dst + c) = v;
    }
}

// ---------------------------------------------------------------------------
// Kernel 1: h = F @ W + b; LayerNorm; L2-normalize -> sem (bf16), bf16 MFMA.
// Block: 512 threads = 8 waves = 4 n-slices (ns) x 2 k-halves (kh).
// Tile: TM=64 rows x full P=128 cols. Each wave: 64 rows x 32 cols x K/2.
// Per-thread B state: bfrag[2][4] = 32 VGPR (was 64 -> spilled last round).
__global__ __launch_bounds__(512, 4)
void proj_mfma_kernel(const float* __restrict__ F,
                      const __hip_bfloat16* __restrict__ Wt,
                      const float* __restrict__ bp, const float* __restrict__ gam,
                      const float* __restrict__ bet, __hip_bfloat16* __restrict__ sem)
{
    // Abuf (64 rows x 512 B, swizzled) overlaid later by comb (64 x 129 f32)
    __shared__ char  lds_main[TM * 129 * 4];  // 33024 B
    __shared__ float red[4][TM][2];           // 2 KB cross-wave reductions

    const int t    = threadIdx.x;
    const int w    = t >> 6;
    const int ns   = w & 3;                   // n-slice: cols [32ns, 32ns+32)
    const int kh   = w >> 2;                  // k-half: k in [128kh, 128kh+128)
    const int lane = t & 63;
    const int cl   = lane & 15;
    const int lg   = lane >> 4;
    const size_t row0 = (size_t)blockIdx.x * TM;

    // ---- B fragments: wave's 32-col x 128-k slice from Wt (L2-resident)
    short8 bfrag[2][4];
#pragma unroll
    for (int n = 0; n < 2; n++)
#pragma unroll
        for (int ks = 0; ks < 4; ks++) {
            const __hip_bfloat16* bsrc =
                Wt + (size_t)(ns * 32 + n * 16 + cl) * Cn + kh * 128 + ks * 32 + lg * 8;
            bfrag[n][ks] = *(const short8*)bsrc;
        }

    // ---- Stage A: 64x256 f32 -> bf16 LDS, one vmcnt round.
    // chunk ci = 8 f32; per thread 4 chunks; swizzle byte = (kc*16)^((row&7)<<4)
    {
        const float* src = F + (row0 << 8);
        float4 g[4][2];
#pragma unroll
        for (int j = 0; j < 4; j++) {
            const int ci = t + j * 512;
            g[j][0] = *(const float4*)(src + (size_t)ci * 8);
            g[j][1] = *(const float4*)(src + (size_t)ci * 8 + 4);
        }
#pragma unroll
        for (int j = 0; j < 4; j++) {
            const int ci  = t + j * 512;
            const int row = ci >> 5;
            const int kc  = ci & 31;
            short8 v;
            v[0] = (short)f2bf(g[j][0].x); v[1] = (short)f2bf(g[j][0].y);
            v[2] = (short)f2bf(g[j][0].z); v[3] = (short)f2bf(g[j][0].w);
            v[4] = (short)f2bf(g[j][1].x); v[5] = (short)f2bf(g[j][1].y);
            v[6] = (short)f2bf(g[j][1].z); v[7] = (short)f2bf(g[j][1].w);
            const int off = row * 512 + ((kc * 16) ^ ((row & 7) << 4));
            *(short8*)(lds_main + off) = v;
        }
    }
    __syncthreads();

    // ---- MFMA: acc[m][n] covers rows m*16.., cols ns*32+n*16.., k-half kh
    f32x4 acc[4][2] = {};
#pragma unroll
    for (int ks = 0; ks < 4; ks++) {
#pragma unroll
        for (int m = 0; m < 4; m++) {
            const int arow  = m * 16 + cl;
            const int kbyte = kh * 256 + ks * 64 + lg * 16;
            const short8 af = *(const short8*)(
                lds_main + arow * 512 + (kbyte ^ ((arow & 7) << 4)));
#pragma unroll
            for (int n = 0; n < 2; n++)
                acc[m][n] = __builtin_amdgcn_mfma_f32_16x16x32_bf16(
                    af, bfrag[n][ks], acc[m][n], 0, 0, 0);
        }
    }
    __syncthreads();   // Abuf dead; safe to overlay comb

    // ---- Combine k-halves: kh=1 writes partials; kh=0 adds.
    float* comb = (float*)lds_main;           // [64][129] f32, padded stride
    if (kh) {
#pragma unroll
        for (int m = 0; m < 4; m++)
#pragma unroll
            for (int n = 0; n < 2; n++)
#pragma unroll
                for (int r = 0; r < 4; r++)
                    comb[(m * 16 + lg * 4 + r) * 129 + ns * 32 + n * 16 + cl] =
                        acc[m][n][r];
    }
    __syncthreads();

    const float b0 = bp[ns * 32 + cl],   b1 = bp[ns * 32 + 16 + cl];
    const float g0 = gam[ns * 32 + cl],  g1 = gam[ns * 32 + 16 + cl];
    const float be0 = bet[ns * 32 + cl], be1 = bet[ns * 32 + 16 + cl];

    float hv[4][2][4];
    if (!kh) {
        // h = acc(kh0) + comb(kh1) + bias; LN partial sums per row
#pragma unroll
        for (int m = 0; m < 4; m++)
#pragma unroll
            for (int r = 0; r < 4; r++) {
                const int row = m * 16 + lg * 4 + r;
                const float h0 = acc[m][0][r] + comb[row * 129 + ns * 32 + cl] + b0;
                const float h1 = acc[m][1][r] + comb[row * 129 + ns * 32 + 16 + cl] + b1;
                hv[m][0][r] = h0; hv[m][1][r] = h1;
                float s = h0 + h1, q = h0 * h0 + h1 * h1;
#pragma unroll
                for (int o = 1; o < 16; o <<= 1) {
                    s += __shfl_xor(s, o);
                    q += __shfl_xor(q, o);
                }
                if (cl == 0) { red[ns][row][0] = s; red[ns][row][1] = q; }
            }
    }
    __syncthreads();
    if (t < TM) {
        float s = 0.f, q = 0.f;
#pragma unroll
        for (int i = 0; i < 4; i++) { s += red[i][t][0]; q += red[i][t][1]; }
        const float mu  = s * (1.f / Pn);
        const float var = q * (1.f / Pn) - mu * mu;
        red[0][t][0] = mu;
        red[0][t][1] = rsqrtf(var + LN_EPSf);
    }
    __syncthreads();

    if (!kh) {
#pragma unroll
        for (int m = 0; m < 4; m++)
#pragma unroll
            for (int r = 0; r < 4; r++) {
                const int row = m * 16 + lg * 4 + r;
                const float mu  = red[0][row][0];
                const float inv = red[0][row][1];
                hv[m][0][r] = (hv[m][0][r] - mu) * inv * g0 + be0;
                hv[m][1][r] = (hv[m][1][r] - mu) * inv * g1 + be1;
            }
    }
    __syncthreads();   // mu/inv consumed before red reuse

    if (!kh) {
#pragma unroll
        for (int m = 0; m < 4; m++)
#pragma unroll
            for (int r = 0; r < 4; r++) {
                float q = hv[m][0][r] * hv[m][0][r] + hv[m][1][r] * hv[m][1][r];
#pragma unroll
                for (int o = 1; o < 16; o <<= 1) q += __shfl_xor(q, o);
                if (cl == 0) red[ns][m * 16 + lg * 4 + r][0] = q;
            }
    }
    __syncthreads();
    if (t < TM) {
        float q = 0.f;
#pragma unroll
        for (int i = 0; i < 4; i++) q += red[i][t][0];
        red[0][t][1] = 1.f / fmaxf(sqrtf(q), 1e-12f);
    }
    __syncthreads();

    if (!kh) {
#pragma unroll
        for (int m = 0; m < 4; m++)
#pragma unroll
            for (int r = 0; r < 4; r++) {
                const int row = m * 16 + lg * 4 + r;
                const float rin = red[0][row][1];
#pragma unroll
                for (int n = 0; n < 2; n++) {
                    const size_t col = ns * 32 + n * 16 + cl;
                    *reinterpret_cast<unsigned short*>(
                        sem + (row0 + row) * Pn + col) = f2bf(hv[m][n][r] * rin);
                }
            }
    }
}

// ---------------------------------------------------------------------------
// Kernel 2: per-edge semantic dot + spatial sim; outputs FLOAT32.
// 16 lanes per edge, 16 edges per 256-thread block.
__global__ __launch_bounds__(256)
void edge_kernel(const __hip_bfloat16* __restrict__ sem,
                 const float* __restrict__ coords,
                 const int* __restrict__ eidx,
                 const float* __restrict__ alpha,
                 float* __restrict__ out_idx,
                 float* __restrict__ out_w)
{
    const int t   = threadIdx.x;
    const int g   = blockIdx.x * 16 + (t >> 4);   // flat edge id = b*E + e
    const int sub = t & 15;
    const int b   = g / En;

    const int src = eidx[(size_t)g * 2 + 0];
    const int dst = eidx[(size_t)g * 2 + 1];

    const size_t srow = ((size_t)b * Ln + src) * Pn;
    const size_t drow = ((size_t)b * Ln + dst) * Pn;

    const short8 sv = *(const short8*)(sem + srow + sub * 8);
    const short8 dv = *(const short8*)(sem + drow + sub * 8);

    float dotv = 0.f;
#pragma unroll
    for (int j = 0; j < 8; j++)
        dotv = fmaf(bf2f((unsigned short)sv[j]), bf2f((unsigned short)dv[j]), dotv);

    for (int o = 1; o < 16; o <<= 1) dotv += __shfl_xor(dotv, o);

    if (sub == 0) {
        const float a = 1.f / (1.f + expf(-alpha[0]));
        const size_t sc = ((size_t)b * Ln + src) * 2;
        const size_t dc = ((size_t)b * Ln + dst) * 2;
        const float ddx = coords[sc + 0] - coords[dc + 0];
        const float ddy = coords[sc + 1] - coords[dc + 1];
        const float dist = sqrtf(ddx * ddx + ddy * ddy + 1e-8f);
        const float ssim = 1.f - dist / 1.414f;
        const float wgt  = a * dotv + (1.f - a) * ssim;
        out_w[g] = wgt;
        out_idx[(size_t)g * 2 + 0] = (float)src;
        out_idx[(size_t)g * 2 + 1] = (float)dst;
    }
}

extern "C" void kernel_launch(void* const* d_in, const int* in_sizes, int n_in,
                              void* d_out, int out_size, void* d_ws, size_t ws_size,
                              hipStream_t stream) {
    const float* F      = (const float*)d_in[0];   // (B,L,C)
    const float* coords = (const float*)d_in[1];   // (B,L,2)
    const int*   eidx   = (const int*)d_in[2];     // (B,E,2)
    const float* alpha  = (const float*)d_in[3];   // scalar
    const float* Wp     = (const float*)d_in[4];   // (C,P)
    const float* bp     = (const float*)d_in[5];   // (P,)
    const float* gam    = (const float*)d_in[6];   // (P,)
    const float* bet    = (const float*)d_in[7];   // (P,)

    float* out     = (float*)d_out;                 // f32 outputs, concat order:
    float* out_idx = out;                           // edge_index (B,E,2) as f32
    float* out_w   = out + (size_t)Bn * En * 2;     // edge_weights (B,E) as f32

    __hip_bfloat16* Wt  = (__hip_bfloat16*)d_ws;               // 64 KB
    __hip_bfloat16* sem = (__hip_bfloat16*)((char*)d_ws + Cn * Pn * 2); // 32 MB

    wt_prep<<<4, 256, 0, stream>>>(Wp, Wt);
    proj_mfma_kernel<<<(Bn * Ln) / TM, 512, 0, stream>>>(F, Wt, bp, gam, bet, sem);
    edge_kernel<<<(Bn * En) / 16, 256, 0, stream>>>(sem, coords, eidx, alpha, out_idx, out_w);
}